// Round 1
// 202.161 us; speedup vs baseline: 1.0775x; 1.0775x over previous
//
#include <hip/hip_runtime.h>

#define KCODES 512
#define DIM    64
#define PXB    512   // pixels per block (2 images)
#define NCT    32    // 16-code tiles covering all 512 codes

typedef __attribute__((ext_vector_type(8))) short  short8;   // 8 bf16 = 4 VGPRs
typedef __attribute__((ext_vector_type(4))) float  floatx4;  // MFMA C/D

__device__ inline unsigned short f2bf(float x) {             // RNE fp32->bf16
    unsigned u = __float_as_uint(x);
    return (unsigned short)((u + 0x7FFFu + ((u >> 16) & 1u)) >> 16);
}
__device__ inline float bf2f(unsigned short h) { return __uint_as_float(((unsigned)h) << 16); }

// --- setup (fuses old prep + cvt + memset) --------------------------------
// enorm: serial fmaf per code (bit-identical to previous kernel).
// e -> bf16 hi/lo of (-2e), stored PRE-SWIZZLED: granule p of code c holds
// dims ((p ^ (c&7))*8 .. +7).  Main stages LDS linearly, reads with the XOR
// -> ds_read_b128 bank conflicts drop 16-way -> ~2-way (free).
// Also zeroes counts + the last-block ticket.
__global__ __launch_bounds__(256) void vq_setup(const float* __restrict__ e,
        float* __restrict__ enorm, unsigned short* __restrict__ ehs,
        unsigned short* __restrict__ els, float* __restrict__ counts,
        unsigned* __restrict__ tick)
{
    const int tg = blockIdx.x * 256 + threadIdx.x;   // 0 .. 512*64-1
    const int c = tg >> 6, j = tg & 63;
    const int p = j >> 3, i = j & 7;
    const int dsrc = ((p ^ (c & 7)) << 3) | i;
    float x = -2.f * e[c * DIM + dsrc];
    unsigned short h = f2bf(x);
    ehs[tg] = h;
    els[tg] = f2bf(x - bf2f(h));
    if (tg < KCODES) {
        const float* er = e + tg * DIM;
        float s = 0.f;
        #pragma unroll
        for (int d = 0; d < DIM; ++d) s = fmaf(er[d], er[d], s);
        enorm[tg]  = s;
        counts[tg] = 0.f;
        if (tg == 0) *tick = 0u;
    }
}

// --- main -----------------------------------------------------------------
// Role swap vs previous version: A = z (pixels, registers: 8 short8/wave),
// B = e hi/lo (ALL 512 codes, LDS 128 KB).  16 waves x 32 px = 512 px/block.
// Wave scans all 512 codes for its own pixels -> no cross-wave combine, no
// barrier in the main loop.  D layout: col = lane&15 = code, row = g4*4+r =
// pixel -> per lane: 4 pixels x 1 code, argmin tracked as (bestv, best_ct).
// MFMA term order identical to previous kernel (zh*eL == eL*zh etc.) ->
// scores bit-identical -> absmax 0.0 preserved.
__global__ __launch_bounds__(1024) void vq_main(
        const float* __restrict__ z, const float* __restrict__ e,
        const unsigned short* __restrict__ ehs, const unsigned short* __restrict__ els,
        const float* __restrict__ enorm, const float* __restrict__ N,
        float* __restrict__ zq, float* __restrict__ counts,
        unsigned* __restrict__ tick, float* __restrict__ outN)
{
    __shared__ __align__(16) unsigned short eHs[KCODES * DIM];  // 64 KB (swizzled)
    __shared__ __align__(16) unsigned short eLs[KCODES * DIM];  // 64 KB (swizzled)
    __shared__ float ens[KCODES];                               // 2 KB
    __shared__ int   hist[KCODES];                              // 2 KB
    __shared__ int   idxs[PXB];                                 // 2 KB
    __shared__ int   lastflag;

    const int t    = threadIdx.x;
    const int b    = blockIdx.x;
    const int lane = t & 63;
    const int wave = t >> 6;        // 0..15
    const int n16  = lane & 15;     // A: pixel row / B: code col
    const int g4   = lane >> 4;     // k-group

    // ---- stage e tables: linear copy (tables pre-swizzled by vq_setup) ----
    {
        const short8* sh = (const short8*)ehs;
        const short8* sl = (const short8*)els;
        short8* dh = (short8*)eHs;
        short8* dl = (short8*)eLs;
        #pragma unroll
        for (int k = 0; k < 4; ++k) {          // 4096 granules / 1024 threads
            dh[t + k * 1024] = sh[t + k * 1024];
            dl[t + k * 1024] = sl[t + k * 1024];
        }
        if (t < KCODES) { ens[t] = enorm[t]; hist[t] = 0; }
    }

    // ---- z -> registers: wave owns 32 pixels, hi/lo fragments ------------
    // lane: pixel (pt*16 + n16), dims ks*32 + g4*8 .. +7
    const int gp0 = b * PXB + wave * 32;
    short8 Ah[2][2], Al[2][2];
    #pragma unroll
    for (int pt = 0; pt < 2; ++pt) {
        const int gp = gp0 + pt * 16 + n16;
        const int bb = gp >> 8, hw = gp & 255;
        const float* zb = z + (size_t)bb * (DIM * 256) + hw;
        #pragma unroll
        for (int ks = 0; ks < 2; ++ks) {
            float v[8];
            #pragma unroll
            for (int q = 0; q < 8; ++q)
                v[q] = zb[(size_t)(ks * 32 + g4 * 8 + q) * 256];
            short8 hi, lo;
            #pragma unroll
            for (int q = 0; q < 8; ++q) {
                unsigned short h = f2bf(v[q]);
                hi[q] = (short)h;
                lo[q] = (short)f2bf(v[q] - bf2f(h));
            }
            Ah[pt][ks] = hi; Al[pt][ks] = lo;
        }
    }

    __syncthreads();   // e tables + enorm + hist ready (only barrier pre-loop)

    // ---- swizzled LDS read bases (constant across ct: (ct*16)&7 == 0) ----
    const int xr = n16 & 7;
    const int byte_ks0 = n16 * 128 + (((g4    ) ^ xr) << 4);
    const int byte_ks1 = n16 * 128 + (((4 | g4) ^ xr) << 4);
    const char* hb = (const char*)eHs;
    const char* lb = (const char*)eLs;

    float bestv[2][4];
    int   bct[2][4];
    #pragma unroll
    for (int pt = 0; pt < 2; ++pt)
        #pragma unroll
        for (int r = 0; r < 4; ++r) { bestv[pt][r] = 3.4e38f; bct[pt][r] = 0; }

    #pragma unroll 4
    for (int ct = 0; ct < NCT; ++ct) {
        const int cb = ct * 2048;          // 16 codes * 128 B
        short8 Bh0 = *(const short8*)(hb + cb + byte_ks0);
        short8 Bh1 = *(const short8*)(hb + cb + byte_ks1);
        short8 Bl0 = *(const short8*)(lb + cb + byte_ks0);
        short8 Bl1 = *(const short8*)(lb + cb + byte_ks1);
        const float en = ens[ct * 16 + n16];
        #pragma unroll
        for (int pt = 0; pt < 2; ++pt) {
            floatx4 C = {en, en, en, en};
            // identical term order to previous kernel: eL*zh, eH*zl, eH*zh
            C = __builtin_amdgcn_mfma_f32_16x16x32_bf16(Ah[pt][0], Bl0, C, 0, 0, 0);
            C = __builtin_amdgcn_mfma_f32_16x16x32_bf16(Ah[pt][1], Bl1, C, 0, 0, 0);
            C = __builtin_amdgcn_mfma_f32_16x16x32_bf16(Al[pt][0], Bh0, C, 0, 0, 0);
            C = __builtin_amdgcn_mfma_f32_16x16x32_bf16(Al[pt][1], Bh1, C, 0, 0, 0);
            C = __builtin_amdgcn_mfma_f32_16x16x32_bf16(Ah[pt][0], Bh0, C, 0, 0, 0);
            C = __builtin_amdgcn_mfma_f32_16x16x32_bf16(Ah[pt][1], Bh1, C, 0, 0, 0);
            #pragma unroll
            for (int r = 0; r < 4; ++r) {   // ascending ct: strict < = first-min
                float s = C[r];
                if (s < bestv[pt][r]) { bestv[pt][r] = s; bct[pt][r] = ct; }
            }
        }
    }

    // ---- argmin across the 16 code-columns (butterfly over n16) ----------
    #pragma unroll
    for (int pt = 0; pt < 2; ++pt)
        #pragma unroll
        for (int r = 0; r < 4; ++r) {
            float v  = bestv[pt][r];
            int   id = bct[pt][r] * 16 + n16;
            #pragma unroll
            for (int off = 1; off < 16; off <<= 1) {
                float v1 = __shfl_xor(v, off, 16);
                int   i1 = __shfl_xor(id, off, 16);
                if (v1 < v || (v1 == v && i1 < id)) { v = v1; id = i1; }
            }
            if (n16 == 0) {
                const int px = wave * 32 + pt * 16 + g4 * 4 + r;
                idxs[px] = id;
                atomicAdd(&hist[id], 1);
            }
        }

    __syncthreads();

    // ---- gather: 1024 threads = 512 px x 2 dim-halves; coalesced stores --
    {
        const int px = t & 511, dh = (t >> 9) * 32;
        const int bi = idxs[px];
        const int gp = b * PXB + px;
        const int bb = gp >> 8, hw = gp & 255;
        const float4* er4 = (const float4*)(e + bi * DIM + dh);
        float* ob = zq + (size_t)bb * (DIM * 256) + (size_t)dh * 256 + hw;
        #pragma unroll
        for (int q = 0; q < 8; ++q) {
            float4 v = er4[q];
            ob[(size_t)(4 * q + 0) * 256] = v.x;
            ob[(size_t)(4 * q + 1) * 256] = v.y;
            ob[(size_t)(4 * q + 2) * 256] = v.z;
            ob[(size_t)(4 * q + 3) * 256] = v.w;
        }
    }

    if (t < KCODES) { int h = hist[t]; if (h) atomicAdd(&counts[t], (float)h); }

    // ---- fused EMA N-update: last block to finish does it ----------------
    __syncthreads();                       // drains this block's vmem (incl. atomics)
    if (t == 0) {
        __threadfence();                   // publish before taking a ticket
        unsigned o = __hip_atomic_fetch_add(tick, 1u, __ATOMIC_ACQ_REL,
                                            __HIP_MEMORY_SCOPE_AGENT);
        lastflag = (o == gridDim.x - 1u);
    }
    __syncthreads();
    if (lastflag && t < KCODES) {
        float c = __hip_atomic_load(&counts[t], __ATOMIC_RELAXED,
                                    __HIP_MEMORY_SCOPE_AGENT);
        outN[t] = 0.995f * N[t] + 0.005f * c;
    }
}

extern "C" void kernel_launch(void* const* d_in, const int* in_sizes, int n_in,
                              void* d_out, int out_size, void* d_ws, size_t ws_size,
                              hipStream_t stream) {
    const float* z = (const float*)d_in[0];
    const float* e = (const float*)d_in[1];
    const float* N = (const float*)d_in[2];
    float* out = (float*)d_out;
    const int nz     = in_sizes[0];            // B*D*H*W = 16777216
    const int npix   = nz / DIM;               // 262144
    const int blocks = npix / PXB;             // 512

    char* ws = (char*)d_ws;
    float*          enorm  = (float*)(ws);                    // 512 f
    float*          counts = (float*)(ws + 2048);             // 512 f
    unsigned*       tick   = (unsigned*)(ws + 4096);          // 1 u32
    unsigned short* ehs    = (unsigned short*)(ws + 4352);    // 64 KB (swizzled)
    unsigned short* els    = (unsigned short*)(ws + 4352 + KCODES * DIM * 2);

    vq_setup<<<(KCODES * DIM) / 256, 256, 0, stream>>>(e, enorm, ehs, els, counts, tick);
    vq_main<<<blocks, 1024, 0, stream>>>(z, e, ehs, els, enorm, N, out, counts,
                                         tick, out + nz);
}

// Round 2
// 171.689 us; speedup vs baseline: 1.2687x; 1.1775x over previous
//
#include <hip/hip_runtime.h>

#define KCODES 512
#define DIM    64
#define PXB    512   // pixels per block
#define NCT    32    // 16-code tiles covering all 512 codes
#define MARGIN 0.125f   // fp16-score certainty margin (~13 sigma of fp16 err)

typedef __attribute__((ext_vector_type(8))) short    short8;   // 16B granule
typedef __attribute__((ext_vector_type(8))) _Float16 half8;    // MFMA A/B frag
typedef __attribute__((ext_vector_type(4))) float    floatx4;  // MFMA C/D

// --- setup: enorm (serial fmaf, bit-identical to passing kernel), ---------
// e -> fp16(-2e) PRE-SWIZZLED single table (granule p of code c holds dims
// ((p ^ (c&7))*8 .. +7)), zero counts + ticket.
__global__ __launch_bounds__(256) void vq_setup(const float* __restrict__ e,
        float* __restrict__ enorm, _Float16* __restrict__ ehf,
        float* __restrict__ counts, unsigned* __restrict__ tick)
{
    const int tg = blockIdx.x * 256 + threadIdx.x;   // 0 .. 512*64-1
    const int c = tg >> 6, j = tg & 63;
    const int p = j >> 3, i = j & 7;
    const int dsrc = ((p ^ (c & 7)) << 3) | i;
    ehf[tg] = (_Float16)(-2.f * e[c * DIM + dsrc]);
    if (tg < KCODES) {
        const float* er = e + tg * DIM;
        float s = 0.f;
        #pragma unroll
        for (int d = 0; d < DIM; ++d) s = fmaf(er[d], er[d], s);
        enorm[tg]  = s;
        counts[tg] = 0.f;
        if (tg == 0) *tick = 0u;
    }
}

// --- main -----------------------------------------------------------------
// A = z fp16 (registers, 4 half8/wave), B = fp16(-2e) ALL 512 codes in LDS
// (64 KB -> 2 blocks/CU -> 8 waves/SIMD).  2 MFMAs per 16x16 tile.
// fp16 score error is handled by margin-certified top-2 + exact fp32 refine
// for ambiguous pixels (same correctness class as fp32 reassociation).
__global__ __launch_bounds__(1024, 8) void vq_main(
        const float* __restrict__ z, const float* __restrict__ e,
        const _Float16* __restrict__ ehf, const float* __restrict__ enorm,
        const float* __restrict__ N, float* __restrict__ zq,
        float* __restrict__ counts, unsigned* __restrict__ tick,
        float* __restrict__ outN)
{
    __shared__ __align__(16) _Float16 eHs[KCODES * DIM];  // 64 KB (swizzled)
    __shared__ float ens[KCODES];                         // 2 KB
    __shared__ int   hist[KCODES];                        // 2 KB
    __shared__ int   idxs[PXB];                           // 2 KB
    __shared__ int   ref2[PXB];                           // 2 KB (runner-up / -1)
    __shared__ int   lastflag;

    const int t    = threadIdx.x;
    const int b    = blockIdx.x;
    const int lane = t & 63;
    const int wave = t >> 6;        // 0..15
    const int n16  = lane & 15;     // A: pixel row / B: code col
    const int g4   = lane >> 4;     // k-group

    // ---- stage e table: linear copy (pre-swizzled in global) -------------
    {
        const short8* src = (const short8*)ehf;
        short8* dst = (short8*)eHs;
        #pragma unroll
        for (int k = 0; k < 4; ++k)           // 4096 granules / 1024 threads
            dst[t + k * 1024] = src[t + k * 1024];
        if (t < KCODES) { ens[t] = enorm[t]; hist[t] = 0; }
    }

    // ---- z -> fp16 registers: wave owns 32 pixels ------------------------
    const int gp0 = b * PXB + wave * 32;
    half8 A[2][2];
    #pragma unroll
    for (int pt = 0; pt < 2; ++pt) {
        const int gp = gp0 + pt * 16 + n16;
        const int bb = gp >> 8, hw = gp & 255;
        const float* zb = z + (size_t)bb * (DIM * 256) + hw;
        #pragma unroll
        for (int ks = 0; ks < 2; ++ks) {
            float v[8];
            #pragma unroll
            for (int q = 0; q < 8; ++q)
                v[q] = zb[(size_t)(ks * 32 + g4 * 8 + q) * 256];
            half8 h;
            #pragma unroll
            for (int q = 0; q < 8; ++q) h[q] = (_Float16)v[q];
            A[pt][ks] = h;
        }
    }

    __syncthreads();   // e table + enorm + hist ready

    // ---- swizzled LDS read bases ((ct*16)&7 == 0 -> constant across ct) --
    const int xr = n16 & 7;
    const int byte0 = n16 * 128 + (((g4    ) ^ xr) << 4);
    const int byte1 = n16 * 128 + (((4 | g4) ^ xr) << 4);
    const char* hb = (const char*)eHs;

    float bestv[2][4];
    int   bct[2][4];
    #pragma unroll
    for (int pt = 0; pt < 2; ++pt)
        #pragma unroll
        for (int r = 0; r < 4; ++r) { bestv[pt][r] = 3.4e38f; bct[pt][r] = 0; }

    #pragma unroll 2
    for (int ct = 0; ct < NCT; ++ct) {
        const int cb = ct * 2048;          // 16 codes * 128 B
        half8 B0 = *(const half8*)(hb + cb + byte0);
        half8 B1 = *(const half8*)(hb + cb + byte1);
        const float en = ens[ct * 16 + n16];
        #pragma unroll
        for (int pt = 0; pt < 2; ++pt) {
            floatx4 C = {en, en, en, en};
            C = __builtin_amdgcn_mfma_f32_16x16x32_f16(A[pt][0], B0, C, 0, 0, 0);
            C = __builtin_amdgcn_mfma_f32_16x16x32_f16(A[pt][1], B1, C, 0, 0, 0);
            #pragma unroll
            for (int r = 0; r < 4; ++r) {   // ascending ct: strict < = first-min
                float s = C[r];
                if (s < bestv[pt][r]) { bestv[pt][r] = s; bct[pt][r] = ct; }
            }
        }
    }

    // ---- per-pixel argmin + runner-up across the 16 code-columns ---------
    #pragma unroll
    for (int pt = 0; pt < 2; ++pt)
        #pragma unroll
        for (int r = 0; r < 4; ++r) {
            const float v1 = bestv[pt][r];
            const int   i1 = bct[pt][r] * 16 + n16;
            // butterfly 1: global best
            float v = v1; int i = i1;
            #pragma unroll
            for (int off = 1; off < 16; off <<= 1) {
                float vs = __shfl_xor(v, off, 16);
                int   is = __shfl_xor(i, off, 16);
                if (vs < v || (vs == v && is < i)) { v = vs; i = is; }
            }
            // butterfly 2: best among lanes excluding the exact winner
            float w  = (i1 == i) ? 3.4e38f : v1;
            int   wi = i1;
            #pragma unroll
            for (int off = 1; off < 16; off <<= 1) {
                float vs = __shfl_xor(w, off, 16);
                int   is = __shfl_xor(wi, off, 16);
                if (vs < w || (vs == w && is < wi)) { w = vs; wi = is; }
            }
            if (n16 == 0) {
                const int px = wave * 32 + pt * 16 + g4 * 4 + r;
                idxs[px] = i;
                ref2[px] = (w - v < MARGIN) ? wi : -1;
            }
        }

    __syncthreads();

    // ---- exact fp32 refine for ambiguous pixels, then histogram ----------
    if (t < PXB) {
        int bi = idxs[t];
        const int r2 = ref2[t];
        if (r2 >= 0) {
            const int gp = b * PXB + t;
            const int bb = gp >> 8, hw = gp & 255;
            const float* zb = z + (size_t)bb * (DIM * 256) + hw;
            const float* e1 = e + bi * DIM;
            const float* e2 = e + r2 * DIM;
            float d1 = 0.f, d2 = 0.f;
            #pragma unroll
            for (int d = 0; d < DIM; ++d) {
                const float zd = zb[(size_t)d * 256];
                d1 = fmaf(zd, e1[d], d1);
                d2 = fmaf(zd, e2[d], d2);
            }
            const float s1 = fmaf(-2.f, d1, ens[bi]);
            const float s2 = fmaf(-2.f, d2, ens[r2]);
            if (s2 < s1 || (s2 == s1 && r2 < bi)) bi = r2;
            idxs[t] = bi;
        }
        atomicAdd(&hist[bi], 1);
    }

    __syncthreads();   // idxs final + hist complete

    // ---- counts + ticket BEFORE the big gather stores --------------------
    if (t < KCODES) { int h = hist[t]; if (h) atomicAdd(&counts[t], (float)h); }
    __syncthreads();                       // drains this block's count atomics
    if (t == 0) {
        __threadfence();
        unsigned o = __hip_atomic_fetch_add(tick, 1u, __ATOMIC_ACQ_REL,
                                            __HIP_MEMORY_SCOPE_AGENT);
        lastflag = (o == gridDim.x - 1u);
    }
    __syncthreads();

    // ---- gather: 1024 threads = 512 px x 2 dim-halves; coalesced stores --
    {
        const int px = t & 511, dh = (t >> 9) * 32;
        const int bi = idxs[px];
        const int gp = b * PXB + px;
        const int bb = gp >> 8, hw = gp & 255;
        const float4* er4 = (const float4*)(e + bi * DIM + dh);
        float* ob = zq + (size_t)bb * (DIM * 256) + (size_t)dh * 256 + hw;
        #pragma unroll
        for (int q = 0; q < 8; ++q) {
            float4 v = er4[q];
            ob[(size_t)(4 * q + 0) * 256] = v.x;
            ob[(size_t)(4 * q + 1) * 256] = v.y;
            ob[(size_t)(4 * q + 2) * 256] = v.z;
            ob[(size_t)(4 * q + 3) * 256] = v.w;
        }
    }

    // ---- fused EMA N-update: last block (ticket taken pre-gather) --------
    if (lastflag && t < KCODES) {
        float c = __hip_atomic_load(&counts[t], __ATOMIC_RELAXED,
                                    __HIP_MEMORY_SCOPE_AGENT);
        outN[t] = 0.995f * N[t] + 0.005f * c;
    }
}

extern "C" void kernel_launch(void* const* d_in, const int* in_sizes, int n_in,
                              void* d_out, int out_size, void* d_ws, size_t ws_size,
                              hipStream_t stream) {
    const float* z = (const float*)d_in[0];
    const float* e = (const float*)d_in[1];
    const float* N = (const float*)d_in[2];
    float* out = (float*)d_out;
    const int nz     = in_sizes[0];            // B*D*H*W = 16777216
    const int npix   = nz / DIM;               // 262144
    const int blocks = npix / PXB;             // 512

    char* ws = (char*)d_ws;
    float*     enorm  = (float*)(ws);                 // 512 f
    float*     counts = (float*)(ws + 2048);          // 512 f
    unsigned*  tick   = (unsigned*)(ws + 4096);       // 1 u32
    _Float16*  ehf    = (_Float16*)(ws + 4352);       // 64 KB (swizzled)

    vq_setup<<<(KCODES * DIM) / 256, 256, 0, stream>>>(e, enorm, ehf, counts, tick);
    vq_main<<<blocks, 1024, 0, stream>>>(z, e, ehf, enorm, N, out, counts,
                                         tick, out + nz);
}

// Round 3
// 167.749 us; speedup vs baseline: 1.2985x; 1.0235x over previous
//
#include <hip/hip_runtime.h>

#define KCODES 512
#define DIM    64
#define PXB    512
#define NCT    32
#define MARGIN 0.125f

typedef __attribute__((ext_vector_type(8))) short        short8;
typedef __attribute__((ext_vector_type(8))) _Float16     half8;
typedef __attribute__((ext_vector_type(4))) float        floatx4;
typedef __attribute__((ext_vector_type(2))) unsigned int uint2v;

__device__ __host__ inline int sigma_dim(int p) {
    return ((p >> 5) << 5) + (((p >> 2) & 1) << 4) + (((p >> 3) & 3) << 2) + (p & 3);
}

__global__ __launch_bounds__(256) void vq_setup(const float* __restrict__ e,
        float* __restrict__ enorm, _Float16* __restrict__ ehf,
        float* __restrict__ counts, unsigned* __restrict__ tick)
{
    const int tg = blockIdx.x * 256 + threadIdx.x;
    const int c = tg >> 6, j = tg & 63;
    const int g = j >> 3, i = j & 7;
    const int gs = g ^ (c & 7);
    const int dsrc = sigma_dim(gs * 8 + i);
    ehf[tg] = (_Float16)(-2.f * e[c * DIM + dsrc]);
    if (tg < KCODES) {
        const float* er = e + tg * DIM;
        float s = 0.f;
        #pragma unroll
        for (int d = 0; d < DIM; ++d) s = fmaf(er[d], er[d], s);
        enorm[tg]  = s;
        counts[tg] = 0.f;
        if (tg == 0) *tick = 0u;
    }
}

__device__ inline unsigned mono(float f) {
    unsigned u = __float_as_uint(f);
    return (u & 0x80000000u) ? ~u : (u | 0x80000000u);
}
__device__ inline float unmono(unsigned u) {
    return __uint_as_float((u & 0x80000000u) ? (u & 0x7FFFFFFFu) : ~u);
}

#define DPP64(dst, src, CTRL) {                                                       \
    int _lo = __builtin_amdgcn_update_dpp(0, (int)(unsigned)((src) & 0xFFFFFFFFull),  \
                                          CTRL, 0xF, 0xF, true);                      \
    int _hi = __builtin_amdgcn_update_dpp(0, (int)(unsigned)((src) >> 32),            \
                                          CTRL, 0xF, 0xF, true);                      \
    dst = (((unsigned long long)(unsigned)_hi) << 32) | (unsigned)_lo; }

#define MERGE_STEP(CTRL) {                                                            \
    unsigned long long o1, o2; DPP64(o1, k1, CTRL); DPP64(o2, k2, CTRL);              \
    unsigned long long mx  = k1 > o1 ? k1 : o1;                                       \
    unsigned long long mn2 = k2 < o2 ? k2 : o2;                                       \
    k1 = k1 < o1 ? k1 : o1;                                                           \
    k2 = mx < mn2 ? mx : mn2; }

__global__ __launch_bounds__(1024, 8) void vq_main(
        const float* __restrict__ z, const float* __restrict__ e,
        const _Float16* __restrict__ ehf, const float* __restrict__ enorm,
        const float* __restrict__ N, float* __restrict__ zq,
        float* __restrict__ counts, unsigned* __restrict__ tick,
        float* __restrict__ outN)
{
    __shared__ __align__(16) _Float16 S[KCODES * DIM];  // 64 KB: z-tile, then e-table
    __shared__ float ens[KCODES];
    __shared__ int   hist[KCODES];
    __shared__ int   idxs[PXB];
    __shared__ int   ref2[PXB];
    __shared__ int   lastflag;

    const int t    = threadIdx.x;
    const int b    = blockIdx.x;
    const int lane = t & 63;
    const int wave = t >> 6;
    const int n16  = lane & 15;
    const int g4   = lane >> 4;

    if (t < KCODES) { ens[t] = enorm[t]; hist[t] = 0; }

    // ---- phase 1: z stage, float4-coalesced -> fp16 LDS tile ---------------
    {
        float4 v[8];
        #pragma unroll
        for (int i = 0; i < 8; ++i) {
            const int L  = i * 1024 + t;
            const int bb = L >> 12, d = (L >> 6) & 63, c4 = L & 63;
            v[i] = *(const float4*)(z + (size_t)((b * 2 + bb) * DIM + d) * 256 + c4 * 4);
        }
        #pragma unroll
        for (int i = 0; i < 8; ++i) {
            const int L  = i * 1024 + t;
            const int bb = L >> 12, d = (L >> 6) & 63, c4 = L & 63;
            union { _Float16 h[4]; uint2v u; } pk;
            pk.h[0] = (_Float16)v[i].x; pk.h[1] = (_Float16)v[i].y;
            pk.h[2] = (_Float16)v[i].z; pk.h[3] = (_Float16)v[i].w;
            const int chunk = bb * 16 + (c4 >> 2);
            *(uint2v*)(S + chunk * 1024 + d * 16 + (c4 & 3) * 4) = pk.u;
        }
    }
    __syncthreads();

    // ---- phase 2: A-fragments via ds_read_b64_tr_b16 -----------------------
    half8 A[2][2];
    {
        uint2v r[2][2][2];
        const int trb = n16 * 2 + g4 * 128;
        #pragma unroll
        for (int pt = 0; pt < 2; ++pt) {
            const int base = (wave * 2 + pt) * 2048 + trb;
            #pragma unroll
            for (int ks = 0; ks < 2; ++ks) {
                const int a0 = base + ks * 1024;
                asm volatile("ds_read_b64_tr_b16 %0, %1" : "=v"(r[pt][ks][0]) : "v"(a0));
                asm volatile("ds_read_b64_tr_b16 %0, %1" : "=v"(r[pt][ks][1]) : "v"(a0 + 512));
            }
        }
        asm volatile("s_waitcnt lgkmcnt(0)" ::: "memory");
        __builtin_amdgcn_sched_barrier(0);
        #pragma unroll
        for (int pt = 0; pt < 2; ++pt)
            #pragma unroll
            for (int ks = 0; ks < 2; ++ks) {
                union { unsigned int u[4]; half8 h; } pk;
                pk.u[0] = r[pt][ks][0].x; pk.u[1] = r[pt][ks][0].y;
                pk.u[2] = r[pt][ks][1].x; pk.u[3] = r[pt][ks][1].y;
                A[pt][ks] = pk.h;
            }
    }
    __syncthreads();   // tr-reads complete -> safe to overwrite S

    // ---- phase 3: e-table stage --------------------------------------------
    {
        const short8* src = (const short8*)ehf;
        short8* dst = (short8*)S;
        #pragma unroll
        for (int k = 0; k < 4; ++k)
            dst[t + k * 1024] = src[t + k * 1024];
    }
    __syncthreads();

    // ---- phase 4: score loop ----------------------------------------------
    const int xr = n16 & 7;
    const int byte0 = n16 * 128 + (((g4    ) ^ xr) << 4);
    const int byte1 = n16 * 128 + (((4 | g4) ^ xr) << 4);
    const char* hb = (const char*)S;

    float bestv[2][4];
    int   bct[2][4];
    #pragma unroll
    for (int pt = 0; pt < 2; ++pt)
        #pragma unroll
        for (int r = 0; r < 4; ++r) { bestv[pt][r] = 3.4e38f; bct[pt][r] = 0; }

    #pragma unroll 2
    for (int ct = 0; ct < NCT; ++ct) {
        const int cb = ct * 2048;
        half8 B0 = *(const half8*)(hb + cb + byte0);
        half8 B1 = *(const half8*)(hb + cb + byte1);
        const float en = ens[ct * 16 + n16];
        #pragma unroll
        for (int pt = 0; pt < 2; ++pt) {
            floatx4 C = {en, en, en, en};
            C = __builtin_amdgcn_mfma_f32_16x16x32_f16(A[pt][0], B0, C, 0, 0, 0);
            C = __builtin_amdgcn_mfma_f32_16x16x32_f16(A[pt][1], B1, C, 0, 0, 0);
            #pragma unroll
            for (int r = 0; r < 4; ++r) {
                float s = C[r];
                if (s < bestv[pt][r]) { bestv[pt][r] = s; bct[pt][r] = ct; }
            }
        }
    }

    // ---- phase 5: DPP top-2 argmin (no LDS ops, no hist yet) ---------------
    #pragma unroll
    for (int pt = 0; pt < 2; ++pt)
        #pragma unroll
        for (int r = 0; r < 4; ++r) {
            unsigned long long k1 =
                (((unsigned long long)mono(bestv[pt][r])) << 32)
                | (unsigned)(bct[pt][r] * 16 + n16);
            unsigned long long k2 = ~0ull;
            MERGE_STEP(0xB1);   // quad_perm [1,0,3,2]
            MERGE_STEP(0x4E);   // quad_perm [2,3,0,1]
            MERGE_STEP(0x124);  // row_ror:4
            MERGE_STEP(0x128);  // row_ror:8
            if (n16 == 0) {
                const int px = wave * 32 + pt * 16 + g4 * 4 + r;
                const float f1 = unmono((unsigned)(k1 >> 32));
                const float f2 = unmono((unsigned)(k2 >> 32));
                idxs[px] = (int)(k1 & 0xFFFFFFFFull);
                ref2[px] = (f2 - f1 < MARGIN) ? (int)(k2 & 0xFFFFFFFFull) : -1;
            }
        }

    __syncthreads();

    // ---- phase 6a: exact refine, then histogram final ids ------------------
    if (t < PXB) {
        int bi = idxs[t];
        const int r2 = ref2[t];
        if (r2 >= 0) {
            const int gp = b * PXB + t;
            const int bb = gp >> 8, hw = gp & 255;
            const float* zb = z + (size_t)bb * (DIM * 256) + hw;
            const float* e1 = e + bi * DIM;
            const float* e2 = e + r2 * DIM;
            float d1 = 0.f, d2 = 0.f;
            #pragma unroll
            for (int d = 0; d < DIM; ++d) {
                const float zd = zb[(size_t)d * 256];
                d1 = fmaf(zd, e1[d], d1);
                d2 = fmaf(zd, e2[d], d2);
            }
            const float s1 = fmaf(-2.f, d1, ens[bi]);
            const float s2 = fmaf(-2.f, d2, ens[r2]);
            if (s2 < s1 || (s2 == s1 && r2 < bi)) bi = r2;
            idxs[t] = bi;
        }
        atomicAdd(&hist[bi], 1);
    }
    __syncthreads();

    // ---- phase 6b: counts + ticket before the big gather -------------------
    if (t < KCODES) { int h = hist[t]; if (h) atomicAdd(&counts[t], (float)h); }
    __syncthreads();
    if (t == 0) {
        __threadfence();
        unsigned o = __hip_atomic_fetch_add(tick, 1u, __ATOMIC_ACQ_REL,
                                            __HIP_MEMORY_SCOPE_AGENT);
        lastflag = (o == gridDim.x - 1u);
    }
    __syncthreads();

    // ---- phase 6c: gather stores ------------------------------------------
    {
        const int px = t & 511, dh = (t >> 9) * 32;
        const int bi = idxs[px];
        const int gp = b * PXB + px;
        const int bb = gp >> 8, hw = gp & 255;
        const float4* er4 = (const float4*)(e + bi * DIM + dh);
        float* ob = zq + (size_t)bb * (DIM * 256) + (size_t)dh * 256 + hw;
        #pragma unroll
        for (int q = 0; q < 8; ++q) {
            float4 v = er4[q];
            ob[(size_t)(4 * q + 0) * 256] = v.x;
            ob[(size_t)(4 * q + 1) * 256] = v.y;
            ob[(size_t)(4 * q + 2) * 256] = v.z;
            ob[(size_t)(4 * q + 3) * 256] = v.w;
        }
    }

    if (lastflag && t < KCODES) {
        float c = __hip_atomic_load(&counts[t], __ATOMIC_RELAXED,
                                    __HIP_MEMORY_SCOPE_AGENT);
        outN[t] = 0.995f * N[t] + 0.005f * c;
    }
}

extern "C" void kernel_launch(void* const* d_in, const int* in_sizes, int n_in,
                              void* d_out, int out_size, void* d_ws, size_t ws_size,
                              hipStream_t stream) {
    const float* z = (const float*)d_in[0];
    const float* e = (const float*)d_in[1];
    const float* N = (const float*)d_in[2];
    float* out = (float*)d_out;
    const int nz     = in_sizes[0];
    const int npix   = nz / DIM;
    const int blocks = npix / PXB;

    char* ws = (char*)d_ws;
    float*     enorm  = (float*)(ws);
    float*     counts = (float*)(ws + 2048);
    unsigned*  tick   = (unsigned*)(ws + 4096);
    _Float16*  ehf    = (_Float16*)(ws + 4352);

    vq_setup<<<(KCODES * DIM) / 256, 256, 0, stream>>>(e, enorm, ehf, counts, tick);
    vq_main<<<blocks, 1024, 0, stream>>>(z, e, ehf, enorm, N, out, counts,
                                         tick, out + nz);
}